// Round 15
// baseline (282.074 us; speedup 1.0000x reference)
//
#include <hip/hip_runtime.h>

typedef unsigned short u16;
typedef __attribute__((ext_vector_type(8))) short short8;
typedef __attribute__((ext_vector_type(4))) float f4;
typedef __attribute__((ext_vector_type(4))) unsigned short u16x4;

#define CN6 524288
#define CN5 65536
#define CN4 8192

__device__ inline u16 f2bf(float f){
  unsigned u = __float_as_uint(f);
  return (u16)((u + 0x7FFFu + ((u >> 16) & 1u)) >> 16);
}
__device__ inline float bf2f(u16 h){ return __uint_as_float(((unsigned)h) << 16); }

__device__ inline f4 nt_load4(const float* p){
  return __builtin_nontemporal_load(reinterpret_cast<const f4*>(p));
}
__device__ inline void nt_store4(float* p, f4 v){
  __builtin_nontemporal_store(v, reinterpret_cast<f4*>(p));
}

// stats layout: sum = stats[0..1056), sq = stats[1056..2112)
// channel offsets: conv10: 0  conv01: 96  conv02: 288  conv12: 672

// ---------------- prep: all 4 weight transposes (f32->bf16) + zero stats ----------------
__global__ __launch_bounds__(256) void k_prep(const float* __restrict__ w10, const float* __restrict__ w01,
                                              const float* __restrict__ w02, const float* __restrict__ w12,
                                              u16* __restrict__ wT10, u16* __restrict__ wT01,
                                              u16* __restrict__ wT02, u16* __restrict__ wT12,
                                              float* __restrict__ stats){
  int i = blockIdx.x * 256 + threadIdx.x;
  if (i < 2112) stats[i] = 0.f;
  if (i < 18432){ int j = i / 192, k = i - j * 192; wT10[i] = f2bf(w10[k * 96 + j]); }
  else if (i < 36864){ int e = i - 18432; int j = e / 96, k = e - j * 96; wT01[e] = f2bf(w01[k * 192 + j]); }
  else if (i < 73728){ int e = i - 36864; int j = e / 96, k = e - j * 96; wT02[e] = f2bf(w02[k * 384 + j]); }
  else if (i < 147456){ int e = i - 73728; int j = e / 192, k = e - j * 192; wT12[e] = f2bf(w12[k * 384 + j]); }
}

// ---------------- fused: data1 f32 -> bf16 LDS tile, pool -> p1, GEMM y10 = d1 @ w10 ----------------
__global__ __launch_bounds__(256) void k_gemm10p(const float* __restrict__ d1, const u16* __restrict__ wT10,
                                                 u16* __restrict__ y10, u16* __restrict__ p1){
  __shared__ u16 sm[64 * 200];       // 64 rows x 192 bf16, padded to 200 (400B row)
  int tid = threadIdx.x, bid = blockIdx.x;

  if (tid < 192){
    int p = tid / 24, c8 = tid - p * 24;      // parent-in-block, 8-channel chunk (covers all 192 ch)
    f4 v0[8], v1[8];
    #pragma unroll
    for (int r = 0; r < 8; r++){
      const float* src = d1 + ((size_t)bid * 64 + p * 8 + r) * 192 + c8 * 8;
      v0[r] = *reinterpret_cast<const f4*>(src);
      v1[r] = *reinterpret_cast<const f4*>(src + 4);
    }
    float mx[8];
    #pragma unroll
    for (int q = 0; q < 4; q++){ mx[q] = v0[0][q]; mx[4 + q] = v1[0][q]; }
    #pragma unroll
    for (int r = 0; r < 8; r++){
      short8 h;
      #pragma unroll
      for (int q = 0; q < 4; q++){
        h[q]     = (short)f2bf(v0[r][q]);
        h[4 + q] = (short)f2bf(v1[r][q]);
        if (r){ mx[q] = fmaxf(mx[q], v0[r][q]); mx[4 + q] = fmaxf(mx[4 + q], v1[r][q]); }
      }
      *reinterpret_cast<short8*>(&sm[(p * 8 + r) * 200 + c8 * 8]) = h;
    }
    short8 hp;
    #pragma unroll
    for (int q = 0; q < 8; q++) hp[q] = (short)f2bf(mx[q]);
    *reinterpret_cast<short8*>(p1 + ((size_t)bid * 8 + p) * 192 + c8 * 8) = hp;
  }
  __syncthreads();

  int lane = tid & 63, wave = tid >> 6;
  int colb = lane & 15;
  int k0 = (lane >> 4) * 8, rgrp = (lane >> 4) * 4;
  int arowl = wave * 16 + colb;              // x-row within block (B free dim)
  short8 xf[6];
  #pragma unroll
  for (int s = 0; s < 6; s++) xf[s] = *reinterpret_cast<short8*>(&sm[arowl * 200 + s * 32 + k0]);

  size_t xrow = (size_t)bid * 64 + arowl;
  #pragma unroll
  for (int j = 0; j < 6; j++){
    f4 acc = {0.f, 0.f, 0.f, 0.f};
    const u16* wr = wT10 + (size_t)(j * 16 + colb) * 192 + k0;   // A-frag: weight cols
    #pragma unroll
    for (int s = 0; s < 6; s++)
      acc = __builtin_amdgcn_mfma_f32_16x16x32_bf16(*reinterpret_cast<const short8*>(wr + s * 32), xf[s], acc, 0, 0, 0);
    u16x4 h;
    #pragma unroll
    for (int r = 0; r < 4; r++) h[r] = f2bf(acc[r]);
    *reinterpret_cast<u16x4*>(y10 + xrow * 96 + j * 16 + rgrp) = h;   // 4 consecutive channels
  }
}

// ---------------- stats for conv10: column sum/sumsq over y10 (bf16, L2-hot) ----------------
__global__ __launch_bounds__(192) void k_stats10(const u16* __restrict__ y10, float* __restrict__ stats){
  __shared__ float ls[96], lq[96];
  int tid = threadIdx.x, bid = blockIdx.x;
  if (tid < 96){ ls[tid] = 0.f; lq[tid] = 0.f; }
  __syncthreads();
  int c8 = tid % 12, rl = tid / 12;          // 12 8-ch chunks x 16 rows
  float s1[8], s2[8];
  #pragma unroll
  for (int q = 0; q < 8; q++){ s1[q] = 0.f; s2[q] = 0.f; }
  for (int it = 0; it < 32; it++){
    size_t row = (size_t)bid * 512 + it * 16 + rl;
    short8 h = *reinterpret_cast<const short8*>(y10 + row * 96 + c8 * 8);
    #pragma unroll
    for (int q = 0; q < 8; q++){
      float v = bf2f((u16)h[q]);
      s1[q] += v; s2[q] += v * v;
    }
  }
  #pragma unroll
  for (int q = 0; q < 8; q++){
    atomicAdd(&ls[c8 * 8 + q], s1[q]);
    atomicAdd(&lq[c8 * 8 + q], s2[q]);
  }
  __syncthreads();
  if (tid < 96){ atomicAdd(&stats[tid], ls[tid]); atomicAdd(&stats[1056 + tid], lq[tid]); }
}

// ---------------- out0 = data0 + up(relu(bn(y10))); p0 = pool(data0); p00 = pool(p0) ----------------
// LINEAR mapping (R13): wave = 1024B contiguous nt loads/stores.
__global__ __launch_bounds__(256) void k_out0(const float* __restrict__ d0, const u16* __restrict__ y10,
                                              const float* __restrict__ stats,
                                              const float* __restrict__ g10, const float* __restrict__ b10,
                                              float* __restrict__ out0, u16* __restrict__ p0, u16* __restrict__ p00){
  __shared__ float yv[8][96];        //  3 KB: post-BN-ReLU y10 for the 8 parents
  __shared__ float sd[64][100];      // 25.6 KB: staged data0 tile (row pad 96->100)
  __shared__ float sp[8][96];        //  3 KB: per-parent channel max
  int tid = threadIdx.x, gp = blockIdx.x;

  if (tid < 192){
    int p = tid / 24, c4 = tid - p * 24;
    u16x4 yb = *reinterpret_cast<const u16x4*>(y10 + ((size_t)gp * 8 + p) * 96 + c4 * 4);
    f4 o;
    #pragma unroll
    for (int q = 0; q < 4; q++){
      int c = c4 * 4 + q;
      float m = stats[c] * (1.f / 65536.f);
      float vv = stats[1056 + c] * (1.f / 65536.f) - m * m;
      float a = g10[c] * rsqrtf(vv + 1e-5f);
      float cc = b10[c] - m * a;
      o[q] = fmaxf(bf2f((u16)yb[q]) * a + cc, 0.f);
    }
    *reinterpret_cast<f4*>(&yv[p][c4 * 4]) = o;
  }
  __syncthreads();

  const float* dsrc = d0 + (size_t)gp * 6144;
  float* ddst = out0 + (size_t)gp * 6144;
  f4 v[6];
  #pragma unroll
  for (int i = 0; i < 6; i++) v[i] = nt_load4(dsrc + (i * 256 + tid) * 4);
  #pragma unroll
  for (int i = 0; i < 6; i++){
    int idx = i * 256 + tid;             // f4 index within 64x96 tile
    int row = idx / 24, c4 = idx - row * 24;
    f4 y = *reinterpret_cast<f4*>(&yv[row >> 3][c4 * 4]);
    f4 o;
    #pragma unroll
    for (int q = 0; q < 4; q++) o[q] = v[i][q] + y[q];
    nt_store4(ddst + idx * 4, o);
    *reinterpret_cast<f4*>(&sd[row][c4 * 4]) = v[i];
  }
  __syncthreads();

  if (tid < 192){
    int p = tid / 24, c4 = tid - p * 24;
    f4 m = *reinterpret_cast<f4*>(&sd[p * 8][c4 * 4]);
    #pragma unroll
    for (int r = 1; r < 8; r++){
      f4 x = *reinterpret_cast<f4*>(&sd[p * 8 + r][c4 * 4]);
      #pragma unroll
      for (int q = 0; q < 4; q++) m[q] = fmaxf(m[q], x[q]);
    }
    u16x4 h;
    #pragma unroll
    for (int q = 0; q < 4; q++) h[q] = f2bf(m[q]);
    *reinterpret_cast<u16x4*>(p0 + ((size_t)gp * 8 + p) * 96 + c4 * 4) = h;
    *reinterpret_cast<f4*>(&sp[p][c4 * 4]) = m;
  }
  __syncthreads();
  if (tid < 24){
    f4 m = *reinterpret_cast<f4*>(&sp[0][tid * 4]);
    #pragma unroll
    for (int pp = 1; pp < 8; pp++){
      f4 x = *reinterpret_cast<f4*>(&sp[pp][tid * 4]);
      #pragma unroll
      for (int q = 0; q < 4; q++) m[q] = fmaxf(m[q], x[q]);
    }
    u16x4 h;
    #pragma unroll
    for (int q = 0; q < 4; q++) h[q] = f2bf(m[q]);
    *reinterpret_cast<u16x4*>(p00 + (size_t)gp * 96 + tid * 4) = h;
  }
}

// ---------------- stats-only GEMM body (no y write) ----------------
template<int Ci, int Co>
__device__ __forceinline__ void stats_body(const u16* __restrict__ x, const u16* __restrict__ wT,
                                           float* __restrict__ sum, float* __restrict__ sq,
                                           int bid, float* ls, float* lq){
  int tid = threadIdx.x;
  for (int t = tid; t < Co; t += 256){ ls[t] = 0.f; lq[t] = 0.f; }
  __syncthreads();
  int lane = tid & 63, wave = tid >> 6;
  int arow = bid * 64 + wave * 16 + (lane & 15);
  int k0 = (lane >> 4) * 8;
  constexpr int KS = Ci / 32;
  short8 af[KS];
  const u16* xr = x + (size_t)arow * Ci + k0;
  #pragma unroll
  for (int s = 0; s < KS; s++) af[s] = *reinterpret_cast<const short8*>(xr + s * 32);
  int colb = lane & 15;
  #pragma unroll 4
  for (int j = 0; j < Co / 16; j++){
    int col = j * 16 + colb;
    f4 acc = {0.f, 0.f, 0.f, 0.f};
    const u16* wr = wT + (size_t)col * Ci + k0;
    #pragma unroll
    for (int s = 0; s < KS; s++)
      acc = __builtin_amdgcn_mfma_f32_16x16x32_bf16(af[s], *reinterpret_cast<const short8*>(wr + s * 32), acc, 0, 0, 0);
    float s1 = acc[0] + acc[1] + acc[2] + acc[3];
    float s2 = acc[0]*acc[0] + acc[1]*acc[1] + acc[2]*acc[2] + acc[3]*acc[3];
    atomicAdd(&ls[col], s1);
    atomicAdd(&lq[col], s2);
  }
  __syncthreads();
  for (int t = tid; t < Co; t += 256){ atomicAdd(&sum[t], ls[t]); atomicAdd(&sq[t], lq[t]); }
}

// blocks [0,1024): stats01(p0)  [1024,1152): stats02(p00)  [1152,1280): stats12(p1)
__global__ __launch_bounds__(256) void k_statsAll(const u16* __restrict__ p0, const u16* __restrict__ p00,
                                                  const u16* __restrict__ p1,
                                                  const u16* __restrict__ wT01, const u16* __restrict__ wT02,
                                                  const u16* __restrict__ wT12, float* __restrict__ stats){
  __shared__ float ls[384], lq[384];
  int bid = blockIdx.x;
  if (bid < 1024)      stats_body<96, 192>(p0,  wT01, stats + 96,  stats + 1056 + 96,  bid,        ls, lq);
  else if (bid < 1152) stats_body<96, 384>(p00, wT02, stats + 288, stats + 1056 + 288, bid - 1024, ls, lq);
  else                 stats_body<192,384>(p1,  wT12, stats + 672, stats + 1056 + 672, bid - 1152, ls, lq);
}

// ---------------- out1 = relu(bn(p0 @ w01)) + data1 ----------------
__global__ __launch_bounds__(256) void k_out1(const u16* __restrict__ p0, const u16* __restrict__ wT01,
                                              const float* __restrict__ d1, const float* __restrict__ stats,
                                              const float* __restrict__ g01, const float* __restrict__ b01,
                                              float* __restrict__ out1){
  __shared__ float aL[192], cL[192];
  __shared__ float so[64 * 196];     // 64 rows x 192 f32, stride 196 (16B-aligned, bank-spread)
  int tid = threadIdx.x, bid = blockIdx.x;
  if (tid < 192){
    float m = stats[96 + tid] * (1.f / 65536.f);
    float v = stats[1056 + 96 + tid] * (1.f / 65536.f) - m * m;
    float a = g01[tid] * rsqrtf(v + 1e-5f);
    aL[tid] = a; cL[tid] = b01[tid] - m * a;
  }
  __syncthreads();
  int lane = tid & 63, wave = tid >> 6;
  int colb = lane & 15;
  int k0 = (lane >> 4) * 8, rgrp = (lane >> 4) * 4;
  int rowl = wave * 16 + colb;               // x-row within block
  short8 xf[3];
  const u16* xr = p0 + ((size_t)bid * 64 + rowl) * 96 + k0;
  #pragma unroll
  for (int s = 0; s < 3; s++) xf[s] = *reinterpret_cast<const short8*>(xr + s * 32);
  #pragma unroll 4
  for (int j = 0; j < 12; j++){
    int ch0 = j * 16 + rgrp;
    f4 acc = {0.f, 0.f, 0.f, 0.f};
    const u16* wr = wT01 + (size_t)(j * 16 + colb) * 96 + k0;
    #pragma unroll
    for (int s = 0; s < 3; s++)
      acc = __builtin_amdgcn_mfma_f32_16x16x32_bf16(*reinterpret_cast<const short8*>(wr + s * 32), xf[s], acc, 0, 0, 0);
    f4 o;
    #pragma unroll
    for (int r = 0; r < 4; r++){
      int ch = ch0 + r;
      o[r] = fmaxf(acc[r] * aL[ch] + cL[ch], 0.f);
    }
    *reinterpret_cast<f4*>(&so[rowl * 196 + ch0]) = o;
  }
  __syncthreads();
  const float* d1b = d1 + (size_t)bid * 64 * 192;
  float* o1b = out1 + (size_t)bid * 64 * 192;
  #pragma unroll
  for (int i = 0; i < 12; i++){
    int idx = i * 256 + tid;
    int rl = idx / 48, c4i = idx % 48;
    f4 y = *reinterpret_cast<f4*>(&so[rl * 196 + c4i * 4]);
    int off = rl * 192 + c4i * 4;
    f4 g = nt_load4(d1b + off);
    f4 o;
    #pragma unroll
    for (int q = 0; q < 4; q++) o[q] = y[q] + g[q];
    nt_store4(o1b + off, o);
  }
}

// ---------------- out2 = relu(bn(p00 @ w02)) + relu(bn(p1 @ w12)) ----------------
__global__ __launch_bounds__(256) void k_out2(const u16* __restrict__ p00, const u16* __restrict__ p1,
                                              const u16* __restrict__ wT02, const u16* __restrict__ wT12,
                                              const float* __restrict__ stats,
                                              const float* __restrict__ g02, const float* __restrict__ b02,
                                              const float* __restrict__ g12, const float* __restrict__ b12,
                                              float* __restrict__ out2){
  __shared__ float a2[384], c2[384], a1[384], c1[384];
  __shared__ float so[32 * 392];     // 32 rows x 384 f32, stride 392
  int tid = threadIdx.x, bid = blockIdx.x;
  for (int t = tid; t < 384; t += 256){
    float m = stats[288 + t] * (1.f / 8192.f);
    float v = stats[1056 + 288 + t] * (1.f / 8192.f) - m * m;
    float a = g02[t] * rsqrtf(v + 1e-5f);
    a2[t] = a; c2[t] = b02[t] - m * a;
    m = stats[672 + t] * (1.f / 8192.f);
    v = stats[1056 + 672 + t] * (1.f / 8192.f) - m * m;
    a = g12[t] * rsqrtf(v + 1e-5f);
    a1[t] = a; c1[t] = b12[t] - m * a;
  }
  __syncthreads();
  int lane = tid & 63, wave = tid >> 6;
  int wr2 = wave >> 1, wc = wave & 1;        // wave grid: 2 row-groups x 2 col-halves
  int colb = lane & 15;
  int k0 = (lane >> 4) * 8, rgrp = (lane >> 4) * 4;
  int rowl = wr2 * 16 + colb;
  size_t arow = (size_t)bid * 32 + rowl;
  short8 xA[3], xB[6];
  #pragma unroll
  for (int s = 0; s < 3; s++) xA[s] = *reinterpret_cast<const short8*>(p00 + arow * 96 + k0 + s * 32);
  #pragma unroll
  for (int s = 0; s < 6; s++) xB[s] = *reinterpret_cast<const short8*>(p1 + arow * 192 + k0 + s * 32);
  #pragma unroll 2
  for (int j = 0; j < 12; j++){
    int ch0 = wc * 192 + j * 16 + rgrp;
    int wrow = wc * 192 + j * 16 + colb;
    f4 u = {0.f, 0.f, 0.f, 0.f}, w = {0.f, 0.f, 0.f, 0.f};
    const u16* wra = wT02 + (size_t)wrow * 96 + k0;
    #pragma unroll
    for (int s = 0; s < 3; s++)
      u = __builtin_amdgcn_mfma_f32_16x16x32_bf16(*reinterpret_cast<const short8*>(wra + s * 32), xA[s], u, 0, 0, 0);
    const u16* wrb = wT12 + (size_t)wrow * 192 + k0;
    #pragma unroll
    for (int s = 0; s < 6; s++)
      w = __builtin_amdgcn_mfma_f32_16x16x32_bf16(*reinterpret_cast<const short8*>(wrb + s * 32), xB[s], w, 0, 0, 0);
    f4 o;
    #pragma unroll
    for (int r = 0; r < 4; r++){
      int ch = ch0 + r;
      o[r] = fmaxf(u[r] * a2[ch] + c2[ch], 0.f) + fmaxf(w[r] * a1[ch] + c1[ch], 0.f);
    }
    *reinterpret_cast<f4*>(&so[rowl * 392 + ch0]) = o;
  }
  __syncthreads();
  #pragma unroll
  for (int i = 0; i < 12; i++){
    int idx = i * 256 + tid;
    int rl = idx / 96, c4i = idx % 96;
    f4 v = *reinterpret_cast<f4*>(&so[rl * 392 + c4i * 4]);
    nt_store4(out2 + ((size_t)bid * 32 + rl) * 384 + c4i * 4, v);
  }
}

extern "C" void kernel_launch(void* const* d_in, const int* in_sizes, int n_in,
                              void* d_out, int out_size, void* d_ws, size_t ws_size,
                              hipStream_t stream){
  const float* data0 = (const float*)d_in[0];
  const float* data1 = (const float*)d_in[1];
  const float* w01 = (const float*)d_in[2];
  const float* g01 = (const float*)d_in[3];
  const float* b01 = (const float*)d_in[4];
  const float* w02 = (const float*)d_in[5];
  const float* g02 = (const float*)d_in[6];
  const float* b02 = (const float*)d_in[7];
  const float* w10 = (const float*)d_in[8];
  const float* g10 = (const float*)d_in[9];
  const float* b10 = (const float*)d_in[10];
  const float* w12 = (const float*)d_in[11];
  const float* g12 = (const float*)d_in[12];
  const float* b12 = (const float*)d_in[13];

  float* out0 = (float*)d_out;                 // [524288, 96]
  float* out1 = out0 + (size_t)CN6 * 96;       // [65536, 192]
  float* out2 = out1 + (size_t)CN5 * 192;      // [8192, 384]

  char* ws = (char*)d_ws;
  u16* p1   = (u16*)(ws + 0);                  //  3145728 B
  u16* p0   = (u16*)(ws + 3145728);            // 12582912
  u16* p00  = (u16*)(ws + 15728640);           //  1572864
  u16* y10  = (u16*)(ws + 17301504);           // 12582912
  u16* wT10 = (u16*)(ws + 29884416);           //    36864
  u16* wT01 = (u16*)(ws + 29921280);           //    36864
  u16* wT02 = (u16*)(ws + 29958144);           //    73728
  u16* wT12 = (u16*)(ws + 30031872);           //   147456
  float* stats = (float*)(ws + 30179328);      //     8448 (2112 f32: sum | sq)

  k_prep<<<576, 256, 0, stream>>>(w10, w01, w02, w12, wT10, wT01, wT02, wT12, stats);
  k_gemm10p<<<1024, 256, 0, stream>>>(data1, wT10, y10, p1);
  k_stats10<<<128, 192, 0, stream>>>(y10, stats);
  // MEASUREMENT ROUND: k_out0 launched TWICE (idempotent). dur - 213.8us = cost(out0).
  k_out0<<<8192, 256, 0, stream>>>(data0, y10, stats, g10, b10, out0, p0, p00);
  k_out0<<<8192, 256, 0, stream>>>(data0, y10, stats, g10, b10, out0, p0, p00);
  k_statsAll<<<1280, 256, 0, stream>>>(p0, p00, p1, wT01, wT02, wT12, stats);
  k_out1<<<1024, 256, 0, stream>>>(p0, wT01, data1, stats, g01, b01, out1);
  k_out2<<<256, 256, 0, stream>>>(p00, p1, wT02, wT12, stats, g02, b02, g12, b12, out2);
}

// Round 16
// 279.372 us; speedup vs baseline: 1.0097x; 1.0097x over previous
//
#include <hip/hip_runtime.h>

typedef unsigned short u16;
typedef __attribute__((ext_vector_type(8))) short short8;
typedef __attribute__((ext_vector_type(4))) float f4;
typedef __attribute__((ext_vector_type(4))) unsigned short u16x4;

#define CN6 524288
#define CN5 65536
#define CN4 8192

__device__ inline u16 f2bf(float f){
  unsigned u = __float_as_uint(f);
  return (u16)((u + 0x7FFFu + ((u >> 16) & 1u)) >> 16);
}
__device__ inline float bf2f(u16 h){ return __uint_as_float(((unsigned)h) << 16); }

__device__ inline f4 nt_load4(const float* p){
  return __builtin_nontemporal_load(reinterpret_cast<const f4*>(p));
}
__device__ inline void nt_store4(float* p, f4 v){
  __builtin_nontemporal_store(v, reinterpret_cast<f4*>(p));
}

// stats layout: sum = stats[0..1056), sq = stats[1056..2112)
// channel offsets: conv10: 0  conv01: 96  conv02: 288  conv12: 672

// ---------------- prep: all 4 weight transposes (f32->bf16) + zero stats ----------------
__global__ __launch_bounds__(256) void k_prep(const float* __restrict__ w10, const float* __restrict__ w01,
                                              const float* __restrict__ w02, const float* __restrict__ w12,
                                              u16* __restrict__ wT10, u16* __restrict__ wT01,
                                              u16* __restrict__ wT02, u16* __restrict__ wT12,
                                              float* __restrict__ stats){
  int i = blockIdx.x * 256 + threadIdx.x;
  if (i < 2112) stats[i] = 0.f;
  if (i < 18432){ int j = i / 192, k = i - j * 192; wT10[i] = f2bf(w10[k * 96 + j]); }
  else if (i < 36864){ int e = i - 18432; int j = e / 96, k = e - j * 96; wT01[e] = f2bf(w01[k * 192 + j]); }
  else if (i < 73728){ int e = i - 36864; int j = e / 96, k = e - j * 96; wT02[e] = f2bf(w02[k * 384 + j]); }
  else if (i < 147456){ int e = i - 73728; int j = e / 192, k = e - j * 192; wT12[e] = f2bf(w12[k * 384 + j]); }
}

// ---------------- fused: data1 f32 -> bf16 LDS tile, pool -> p1, GEMM y10 = d1 @ w10 ----------------
__global__ __launch_bounds__(256) void k_gemm10p(const float* __restrict__ d1, const u16* __restrict__ wT10,
                                                 u16* __restrict__ y10, u16* __restrict__ p1){
  __shared__ u16 sm[64 * 200];       // 64 rows x 192 bf16, padded to 200 (400B row)
  int tid = threadIdx.x, bid = blockIdx.x;

  if (tid < 192){
    int p = tid / 24, c8 = tid - p * 24;      // parent-in-block, 8-channel chunk (covers all 192 ch)
    f4 v0[8], v1[8];
    #pragma unroll
    for (int r = 0; r < 8; r++){
      const float* src = d1 + ((size_t)bid * 64 + p * 8 + r) * 192 + c8 * 8;
      v0[r] = *reinterpret_cast<const f4*>(src);
      v1[r] = *reinterpret_cast<const f4*>(src + 4);
    }
    float mx[8];
    #pragma unroll
    for (int q = 0; q < 4; q++){ mx[q] = v0[0][q]; mx[4 + q] = v1[0][q]; }
    #pragma unroll
    for (int r = 0; r < 8; r++){
      short8 h;
      #pragma unroll
      for (int q = 0; q < 4; q++){
        h[q]     = (short)f2bf(v0[r][q]);
        h[4 + q] = (short)f2bf(v1[r][q]);
        if (r){ mx[q] = fmaxf(mx[q], v0[r][q]); mx[4 + q] = fmaxf(mx[4 + q], v1[r][q]); }
      }
      *reinterpret_cast<short8*>(&sm[(p * 8 + r) * 200 + c8 * 8]) = h;
    }
    short8 hp;
    #pragma unroll
    for (int q = 0; q < 8; q++) hp[q] = (short)f2bf(mx[q]);
    *reinterpret_cast<short8*>(p1 + ((size_t)bid * 8 + p) * 192 + c8 * 8) = hp;
  }
  __syncthreads();

  int lane = tid & 63, wave = tid >> 6;
  int colb = lane & 15;
  int k0 = (lane >> 4) * 8, rgrp = (lane >> 4) * 4;
  int arowl = wave * 16 + colb;              // x-row within block (B free dim)
  short8 xf[6];
  #pragma unroll
  for (int s = 0; s < 6; s++) xf[s] = *reinterpret_cast<short8*>(&sm[arowl * 200 + s * 32 + k0]);

  size_t xrow = (size_t)bid * 64 + arowl;
  #pragma unroll
  for (int j = 0; j < 6; j++){
    f4 acc = {0.f, 0.f, 0.f, 0.f};
    const u16* wr = wT10 + (size_t)(j * 16 + colb) * 192 + k0;   // A-frag: weight cols
    #pragma unroll
    for (int s = 0; s < 6; s++)
      acc = __builtin_amdgcn_mfma_f32_16x16x32_bf16(*reinterpret_cast<const short8*>(wr + s * 32), xf[s], acc, 0, 0, 0);
    u16x4 h;
    #pragma unroll
    for (int r = 0; r < 4; r++) h[r] = f2bf(acc[r]);
    *reinterpret_cast<u16x4*>(y10 + xrow * 96 + j * 16 + rgrp) = h;   // 4 consecutive channels
  }
}

// ---------------- stats for conv10: column sum/sumsq over y10 (bf16, L2-hot) ----------------
__global__ __launch_bounds__(192) void k_stats10(const u16* __restrict__ y10, float* __restrict__ stats){
  __shared__ float ls[96], lq[96];
  int tid = threadIdx.x, bid = blockIdx.x;
  if (tid < 96){ ls[tid] = 0.f; lq[tid] = 0.f; }
  __syncthreads();
  int c8 = tid % 12, rl = tid / 12;          // 12 8-ch chunks x 16 rows
  float s1[8], s2[8];
  #pragma unroll
  for (int q = 0; q < 8; q++){ s1[q] = 0.f; s2[q] = 0.f; }
  for (int it = 0; it < 32; it++){
    size_t row = (size_t)bid * 512 + it * 16 + rl;
    short8 h = *reinterpret_cast<const short8*>(y10 + row * 96 + c8 * 8);
    #pragma unroll
    for (int q = 0; q < 8; q++){
      float v = bf2f((u16)h[q]);
      s1[q] += v; s2[q] += v * v;
    }
  }
  #pragma unroll
  for (int q = 0; q < 8; q++){
    atomicAdd(&ls[c8 * 8 + q], s1[q]);
    atomicAdd(&lq[c8 * 8 + q], s2[q]);
  }
  __syncthreads();
  if (tid < 96){ atomicAdd(&stats[tid], ls[tid]); atomicAdd(&stats[1056 + tid], lq[tid]); }
}

// ---------------- out0 = data0 + up(relu(bn(y10))); p0 = pool(data0); p00 = pool(p0) ----------------
// LINEAR mapping (R13): wave = 1024B contiguous nt loads/stores.
__global__ __launch_bounds__(256) void k_out0(const float* __restrict__ d0, const u16* __restrict__ y10,
                                              const float* __restrict__ stats,
                                              const float* __restrict__ g10, const float* __restrict__ b10,
                                              float* __restrict__ out0, u16* __restrict__ p0, u16* __restrict__ p00){
  __shared__ float yv[8][96];        //  3 KB: post-BN-ReLU y10 for the 8 parents
  __shared__ float sd[64][100];      // 25.6 KB: staged data0 tile (row pad 96->100)
  __shared__ float sp[8][96];        //  3 KB: per-parent channel max
  int tid = threadIdx.x, gp = blockIdx.x;

  if (tid < 192){
    int p = tid / 24, c4 = tid - p * 24;
    u16x4 yb = *reinterpret_cast<const u16x4*>(y10 + ((size_t)gp * 8 + p) * 96 + c4 * 4);
    f4 o;
    #pragma unroll
    for (int q = 0; q < 4; q++){
      int c = c4 * 4 + q;
      float m = stats[c] * (1.f / 65536.f);
      float vv = stats[1056 + c] * (1.f / 65536.f) - m * m;
      float a = g10[c] * rsqrtf(vv + 1e-5f);
      float cc = b10[c] - m * a;
      o[q] = fmaxf(bf2f((u16)yb[q]) * a + cc, 0.f);
    }
    *reinterpret_cast<f4*>(&yv[p][c4 * 4]) = o;
  }
  __syncthreads();

  const float* dsrc = d0 + (size_t)gp * 6144;
  float* ddst = out0 + (size_t)gp * 6144;
  f4 v[6];
  #pragma unroll
  for (int i = 0; i < 6; i++) v[i] = nt_load4(dsrc + (i * 256 + tid) * 4);
  #pragma unroll
  for (int i = 0; i < 6; i++){
    int idx = i * 256 + tid;             // f4 index within 64x96 tile
    int row = idx / 24, c4 = idx - row * 24;
    f4 y = *reinterpret_cast<f4*>(&yv[row >> 3][c4 * 4]);
    f4 o;
    #pragma unroll
    for (int q = 0; q < 4; q++) o[q] = v[i][q] + y[q];
    nt_store4(ddst + idx * 4, o);
    *reinterpret_cast<f4*>(&sd[row][c4 * 4]) = v[i];
  }
  __syncthreads();

  if (tid < 192){
    int p = tid / 24, c4 = tid - p * 24;
    f4 m = *reinterpret_cast<f4*>(&sd[p * 8][c4 * 4]);
    #pragma unroll
    for (int r = 1; r < 8; r++){
      f4 x = *reinterpret_cast<f4*>(&sd[p * 8 + r][c4 * 4]);
      #pragma unroll
      for (int q = 0; q < 4; q++) m[q] = fmaxf(m[q], x[q]);
    }
    u16x4 h;
    #pragma unroll
    for (int q = 0; q < 4; q++) h[q] = f2bf(m[q]);
    *reinterpret_cast<u16x4*>(p0 + ((size_t)gp * 8 + p) * 96 + c4 * 4) = h;
    *reinterpret_cast<f4*>(&sp[p][c4 * 4]) = m;
  }
  __syncthreads();
  if (tid < 24){
    f4 m = *reinterpret_cast<f4*>(&sp[0][tid * 4]);
    #pragma unroll
    for (int pp = 1; pp < 8; pp++){
      f4 x = *reinterpret_cast<f4*>(&sp[pp][tid * 4]);
      #pragma unroll
      for (int q = 0; q < 4; q++) m[q] = fmaxf(m[q], x[q]);
    }
    u16x4 h;
    #pragma unroll
    for (int q = 0; q < 4; q++) h[q] = f2bf(m[q]);
    *reinterpret_cast<u16x4*>(p00 + (size_t)gp * 96 + tid * 4) = h;
  }
}

// ---------------- stats-only GEMM body (no y write) ----------------
template<int Ci, int Co>
__device__ __forceinline__ void stats_body(const u16* __restrict__ x, const u16* __restrict__ wT,
                                           float* __restrict__ sum, float* __restrict__ sq,
                                           int bid, float* ls, float* lq){
  int tid = threadIdx.x;
  for (int t = tid; t < Co; t += 256){ ls[t] = 0.f; lq[t] = 0.f; }
  __syncthreads();
  int lane = tid & 63, wave = tid >> 6;
  int arow = bid * 64 + wave * 16 + (lane & 15);
  int k0 = (lane >> 4) * 8;
  constexpr int KS = Ci / 32;
  short8 af[KS];
  const u16* xr = x + (size_t)arow * Ci + k0;
  #pragma unroll
  for (int s = 0; s < KS; s++) af[s] = *reinterpret_cast<const short8*>(xr + s * 32);
  int colb = lane & 15;
  #pragma unroll 4
  for (int j = 0; j < Co / 16; j++){
    int col = j * 16 + colb;
    f4 acc = {0.f, 0.f, 0.f, 0.f};
    const u16* wr = wT + (size_t)col * Ci + k0;
    #pragma unroll
    for (int s = 0; s < KS; s++)
      acc = __builtin_amdgcn_mfma_f32_16x16x32_bf16(af[s], *reinterpret_cast<const short8*>(wr + s * 32), acc, 0, 0, 0);
    float s1 = acc[0] + acc[1] + acc[2] + acc[3];
    float s2 = acc[0]*acc[0] + acc[1]*acc[1] + acc[2]*acc[2] + acc[3]*acc[3];
    atomicAdd(&ls[col], s1);
    atomicAdd(&lq[col], s2);
  }
  __syncthreads();
  for (int t = tid; t < Co; t += 256){ atomicAdd(&sum[t], ls[t]); atomicAdd(&sq[t], lq[t]); }
}

// blocks [0,1024): stats01(p0)  [1024,1152): stats02(p00)  [1152,1280): stats12(p1)
__global__ __launch_bounds__(256) void k_statsAll(const u16* __restrict__ p0, const u16* __restrict__ p00,
                                                  const u16* __restrict__ p1,
                                                  const u16* __restrict__ wT01, const u16* __restrict__ wT02,
                                                  const u16* __restrict__ wT12, float* __restrict__ stats){
  __shared__ float ls[384], lq[384];
  int bid = blockIdx.x;
  if (bid < 1024)      stats_body<96, 192>(p0,  wT01, stats + 96,  stats + 1056 + 96,  bid,        ls, lq);
  else if (bid < 1152) stats_body<96, 384>(p00, wT02, stats + 288, stats + 1056 + 288, bid - 1024, ls, lq);
  else                 stats_body<192,384>(p1,  wT12, stats + 672, stats + 1056 + 672, bid - 1152, ls, lq);
}

// ---------------- out1 = relu(bn(p0 @ w01)) + data1 ----------------
__global__ __launch_bounds__(256) void k_out1(const u16* __restrict__ p0, const u16* __restrict__ wT01,
                                              const float* __restrict__ d1, const float* __restrict__ stats,
                                              const float* __restrict__ g01, const float* __restrict__ b01,
                                              float* __restrict__ out1){
  __shared__ float aL[192], cL[192];
  __shared__ float so[64 * 196];     // 64 rows x 192 f32, stride 196 (16B-aligned, bank-spread)
  int tid = threadIdx.x, bid = blockIdx.x;
  if (tid < 192){
    float m = stats[96 + tid] * (1.f / 65536.f);
    float v = stats[1056 + 96 + tid] * (1.f / 65536.f) - m * m;
    float a = g01[tid] * rsqrtf(v + 1e-5f);
    aL[tid] = a; cL[tid] = b01[tid] - m * a;
  }
  __syncthreads();
  int lane = tid & 63, wave = tid >> 6;
  int colb = lane & 15;
  int k0 = (lane >> 4) * 8, rgrp = (lane >> 4) * 4;
  int rowl = wave * 16 + colb;               // x-row within block
  short8 xf[3];
  const u16* xr = p0 + ((size_t)bid * 64 + rowl) * 96 + k0;
  #pragma unroll
  for (int s = 0; s < 3; s++) xf[s] = *reinterpret_cast<const short8*>(xr + s * 32);
  #pragma unroll 4
  for (int j = 0; j < 12; j++){
    int ch0 = j * 16 + rgrp;
    f4 acc = {0.f, 0.f, 0.f, 0.f};
    const u16* wr = wT01 + (size_t)(j * 16 + colb) * 96 + k0;
    #pragma unroll
    for (int s = 0; s < 3; s++)
      acc = __builtin_amdgcn_mfma_f32_16x16x32_bf16(*reinterpret_cast<const short8*>(wr + s * 32), xf[s], acc, 0, 0, 0);
    f4 o;
    #pragma unroll
    for (int r = 0; r < 4; r++){
      int ch = ch0 + r;
      o[r] = fmaxf(acc[r] * aL[ch] + cL[ch], 0.f);
    }
    *reinterpret_cast<f4*>(&so[rowl * 196 + ch0]) = o;
  }
  __syncthreads();
  const float* d1b = d1 + (size_t)bid * 64 * 192;
  float* o1b = out1 + (size_t)bid * 64 * 192;
  #pragma unroll
  for (int i = 0; i < 12; i++){
    int idx = i * 256 + tid;
    int rl = idx / 48, c4i = idx % 48;
    f4 y = *reinterpret_cast<f4*>(&so[rl * 196 + c4i * 4]);
    int off = rl * 192 + c4i * 4;
    f4 g = nt_load4(d1b + off);
    f4 o;
    #pragma unroll
    for (int q = 0; q < 4; q++) o[q] = y[q] + g[q];
    nt_store4(o1b + off, o);
  }
}

// ---------------- out2 = relu(bn(p00 @ w02)) + relu(bn(p1 @ w12)) ----------------
__global__ __launch_bounds__(256) void k_out2(const u16* __restrict__ p00, const u16* __restrict__ p1,
                                              const u16* __restrict__ wT02, const u16* __restrict__ wT12,
                                              const float* __restrict__ stats,
                                              const float* __restrict__ g02, const float* __restrict__ b02,
                                              const float* __restrict__ g12, const float* __restrict__ b12,
                                              float* __restrict__ out2){
  __shared__ float a2[384], c2[384], a1[384], c1[384];
  __shared__ float so[32 * 392];     // 32 rows x 384 f32, stride 392
  int tid = threadIdx.x, bid = blockIdx.x;
  for (int t = tid; t < 384; t += 256){
    float m = stats[288 + t] * (1.f / 8192.f);
    float v = stats[1056 + 288 + t] * (1.f / 8192.f) - m * m;
    float a = g02[t] * rsqrtf(v + 1e-5f);
    a2[t] = a; c2[t] = b02[t] - m * a;
    m = stats[672 + t] * (1.f / 8192.f);
    v = stats[1056 + 672 + t] * (1.f / 8192.f) - m * m;
    a = g12[t] * rsqrtf(v + 1e-5f);
    a1[t] = a; c1[t] = b12[t] - m * a;
  }
  __syncthreads();
  int lane = tid & 63, wave = tid >> 6;
  int wr2 = wave >> 1, wc = wave & 1;        // wave grid: 2 row-groups x 2 col-halves
  int colb = lane & 15;
  int k0 = (lane >> 4) * 8, rgrp = (lane >> 4) * 4;
  int rowl = wr2 * 16 + colb;
  size_t arow = (size_t)bid * 32 + rowl;
  short8 xA[3], xB[6];
  #pragma unroll
  for (int s = 0; s < 3; s++) xA[s] = *reinterpret_cast<const short8*>(p00 + arow * 96 + k0 + s * 32);
  #pragma unroll
  for (int s = 0; s < 6; s++) xB[s] = *reinterpret_cast<const short8*>(p1 + arow * 192 + k0 + s * 32);
  #pragma unroll 2
  for (int j = 0; j < 12; j++){
    int ch0 = wc * 192 + j * 16 + rgrp;
    int wrow = wc * 192 + j * 16 + colb;
    f4 u = {0.f, 0.f, 0.f, 0.f}, w = {0.f, 0.f, 0.f, 0.f};
    const u16* wra = wT02 + (size_t)wrow * 96 + k0;
    #pragma unroll
    for (int s = 0; s < 3; s++)
      u = __builtin_amdgcn_mfma_f32_16x16x32_bf16(*reinterpret_cast<const short8*>(wra + s * 32), xA[s], u, 0, 0, 0);
    const u16* wrb = wT12 + (size_t)wrow * 192 + k0;
    #pragma unroll
    for (int s = 0; s < 6; s++)
      w = __builtin_amdgcn_mfma_f32_16x16x32_bf16(*reinterpret_cast<const short8*>(wrb + s * 32), xB[s], w, 0, 0, 0);
    f4 o;
    #pragma unroll
    for (int r = 0; r < 4; r++){
      int ch = ch0 + r;
      o[r] = fmaxf(u[r] * a2[ch] + c2[ch], 0.f) + fmaxf(w[r] * a1[ch] + c1[ch], 0.f);
    }
    *reinterpret_cast<f4*>(&so[rowl * 392 + ch0]) = o;
  }
  __syncthreads();
  #pragma unroll
  for (int i = 0; i < 12; i++){
    int idx = i * 256 + tid;
    int rl = idx / 96, c4i = idx % 96;
    f4 v = *reinterpret_cast<f4*>(&so[rl * 392 + c4i * 4]);
    nt_store4(out2 + ((size_t)bid * 32 + rl) * 384 + c4i * 4, v);
  }
}

extern "C" void kernel_launch(void* const* d_in, const int* in_sizes, int n_in,
                              void* d_out, int out_size, void* d_ws, size_t ws_size,
                              hipStream_t stream){
  const float* data0 = (const float*)d_in[0];
  const float* data1 = (const float*)d_in[1];
  const float* w01 = (const float*)d_in[2];
  const float* g01 = (const float*)d_in[3];
  const float* b01 = (const float*)d_in[4];
  const float* w02 = (const float*)d_in[5];
  const float* g02 = (const float*)d_in[6];
  const float* b02 = (const float*)d_in[7];
  const float* w10 = (const float*)d_in[8];
  const float* g10 = (const float*)d_in[9];
  const float* b10 = (const float*)d_in[10];
  const float* w12 = (const float*)d_in[11];
  const float* g12 = (const float*)d_in[12];
  const float* b12 = (const float*)d_in[13];

  float* out0 = (float*)d_out;                 // [524288, 96]
  float* out1 = out0 + (size_t)CN6 * 96;       // [65536, 192]
  float* out2 = out1 + (size_t)CN5 * 192;      // [8192, 384]

  char* ws = (char*)d_ws;
  u16* p1   = (u16*)(ws + 0);                  //  3145728 B
  u16* p0   = (u16*)(ws + 3145728);            // 12582912
  u16* p00  = (u16*)(ws + 15728640);           //  1572864
  u16* y10  = (u16*)(ws + 17301504);           // 12582912
  u16* wT10 = (u16*)(ws + 29884416);           //    36864
  u16* wT01 = (u16*)(ws + 29921280);           //    36864
  u16* wT02 = (u16*)(ws + 29958144);           //    73728
  u16* wT12 = (u16*)(ws + 30031872);           //   147456
  float* stats = (float*)(ws + 30179328);      //     8448 (2112 f32: sum | sq)

  k_prep<<<576, 256, 0, stream>>>(w10, w01, w02, w12, wT10, wT01, wT02, wT12, stats);
  // MEASUREMENT ROUND 2: gemm10p, out1, out2 each launched TWICE (idempotent).
  // dur - 213.8us = cost(gemm10p) + cost(out1) + cost(out2).  [out0 known: 68.3us]
  k_gemm10p<<<1024, 256, 0, stream>>>(data1, wT10, y10, p1);
  k_gemm10p<<<1024, 256, 0, stream>>>(data1, wT10, y10, p1);
  k_stats10<<<128, 192, 0, stream>>>(y10, stats);
  k_out0<<<8192, 256, 0, stream>>>(data0, y10, stats, g10, b10, out0, p0, p00);
  k_statsAll<<<1280, 256, 0, stream>>>(p0, p00, p1, wT01, wT02, wT12, stats);
  k_out1<<<1024, 256, 0, stream>>>(p0, wT01, data1, stats, g01, b01, out1);
  k_out1<<<1024, 256, 0, stream>>>(p0, wT01, data1, stats, g01, b01, out1);
  k_out2<<<256, 256, 0, stream>>>(p00, p1, wT02, wT12, stats, g02, b02, g12, b12, out2);
  k_out2<<<256, 256, 0, stream>>>(p00, p1, wT02, wT12, stats, g02, b02, g12, b12, out2);
}

// Round 17
// 241.189 us; speedup vs baseline: 1.1695x; 1.1583x over previous
//
#include <hip/hip_runtime.h>

typedef unsigned short u16;
typedef __attribute__((ext_vector_type(8))) short short8;
typedef __attribute__((ext_vector_type(4))) float f4;
typedef __attribute__((ext_vector_type(4))) unsigned short u16x4;

#define CN6 524288
#define CN5 65536
#define CN4 8192

__device__ inline u16 f2bf(float f){
  unsigned u = __float_as_uint(f);
  return (u16)((u + 0x7FFFu + ((u >> 16) & 1u)) >> 16);
}
__device__ inline float bf2f(u16 h){ return __uint_as_float(((unsigned)h) << 16); }

__device__ inline f4 nt_load4(const float* p){
  return __builtin_nontemporal_load(reinterpret_cast<const f4*>(p));
}
__device__ inline void nt_store4(float* p, f4 v){
  __builtin_nontemporal_store(v, reinterpret_cast<f4*>(p));
}

// stats layout: sum = stats[0..1056), sq = stats[1056..2112)
// channel offsets: conv10: 0  conv01: 96  conv02: 288  conv12: 672

// ---------------- prep: all 4 weight transposes (f32->bf16) + zero stats ----------------
__global__ __launch_bounds__(256) void k_prep(const float* __restrict__ w10, const float* __restrict__ w01,
                                              const float* __restrict__ w02, const float* __restrict__ w12,
                                              u16* __restrict__ wT10, u16* __restrict__ wT01,
                                              u16* __restrict__ wT02, u16* __restrict__ wT12,
                                              float* __restrict__ stats){
  int i = blockIdx.x * 256 + threadIdx.x;
  if (i < 2112) stats[i] = 0.f;
  if (i < 18432){ int j = i / 192, k = i - j * 192; wT10[i] = f2bf(w10[k * 96 + j]); }
  else if (i < 36864){ int e = i - 18432; int j = e / 96, k = e - j * 96; wT01[e] = f2bf(w01[k * 192 + j]); }
  else if (i < 73728){ int e = i - 36864; int j = e / 96, k = e - j * 96; wT02[e] = f2bf(w02[k * 384 + j]); }
  else if (i < 147456){ int e = i - 73728; int j = e / 192, k = e - j * 192; wT12[e] = f2bf(w12[k * 384 + j]); }
}

// ---------------- fused: data1 f32 -> bf16 LDS tile, pool -> p1, GEMM y10 = d1 @ w10 ----------------
__global__ __launch_bounds__(256) void k_gemm10p(const float* __restrict__ d1, const u16* __restrict__ wT10,
                                                 u16* __restrict__ y10, u16* __restrict__ p1){
  __shared__ u16 sm[64 * 200];       // 64 rows x 192 bf16, padded to 200 (400B row)
  int tid = threadIdx.x, bid = blockIdx.x;

  if (tid < 192){
    int p = tid / 24, c8 = tid - p * 24;      // parent-in-block, 8-channel chunk (covers all 192 ch)
    f4 v0[8], v1[8];
    #pragma unroll
    for (int r = 0; r < 8; r++){
      const float* src = d1 + ((size_t)bid * 64 + p * 8 + r) * 192 + c8 * 8;
      v0[r] = *reinterpret_cast<const f4*>(src);
      v1[r] = *reinterpret_cast<const f4*>(src + 4);
    }
    float mx[8];
    #pragma unroll
    for (int q = 0; q < 4; q++){ mx[q] = v0[0][q]; mx[4 + q] = v1[0][q]; }
    #pragma unroll
    for (int r = 0; r < 8; r++){
      short8 h;
      #pragma unroll
      for (int q = 0; q < 4; q++){
        h[q]     = (short)f2bf(v0[r][q]);
        h[4 + q] = (short)f2bf(v1[r][q]);
        if (r){ mx[q] = fmaxf(mx[q], v0[r][q]); mx[4 + q] = fmaxf(mx[4 + q], v1[r][q]); }
      }
      *reinterpret_cast<short8*>(&sm[(p * 8 + r) * 200 + c8 * 8]) = h;
    }
    short8 hp;
    #pragma unroll
    for (int q = 0; q < 8; q++) hp[q] = (short)f2bf(mx[q]);
    *reinterpret_cast<short8*>(p1 + ((size_t)bid * 8 + p) * 192 + c8 * 8) = hp;
  }
  __syncthreads();

  int lane = tid & 63, wave = tid >> 6;
  int colb = lane & 15;
  int k0 = (lane >> 4) * 8, rgrp = (lane >> 4) * 4;
  int arowl = wave * 16 + colb;              // x-row within block (B free dim)
  short8 xf[6];
  #pragma unroll
  for (int s = 0; s < 6; s++) xf[s] = *reinterpret_cast<short8*>(&sm[arowl * 200 + s * 32 + k0]);

  size_t xrow = (size_t)bid * 64 + arowl;
  #pragma unroll
  for (int j = 0; j < 6; j++){
    f4 acc = {0.f, 0.f, 0.f, 0.f};
    const u16* wr = wT10 + (size_t)(j * 16 + colb) * 192 + k0;   // A-frag: weight cols
    #pragma unroll
    for (int s = 0; s < 6; s++)
      acc = __builtin_amdgcn_mfma_f32_16x16x32_bf16(*reinterpret_cast<const short8*>(wr + s * 32), xf[s], acc, 0, 0, 0);
    u16x4 h;
    #pragma unroll
    for (int r = 0; r < 4; r++) h[r] = f2bf(acc[r]);
    *reinterpret_cast<u16x4*>(y10 + xrow * 96 + j * 16 + rgrp) = h;   // 4 consecutive channels
  }
}

// ---------------- stats for conv10: column sum/sumsq over y10 (L2-hot, occupancy-fixed) ----------------
// 1024 blocks x 64 rows (was 128 x 512 - half-GPU idle).
__global__ __launch_bounds__(192) void k_stats10(const u16* __restrict__ y10, float* __restrict__ stats){
  __shared__ float ls[96], lq[96];
  int tid = threadIdx.x, bid = blockIdx.x;
  if (tid < 96){ ls[tid] = 0.f; lq[tid] = 0.f; }
  __syncthreads();
  int c8 = tid % 12, rl = tid / 12;          // 12 8-ch chunks x 16 rows
  float s1[8], s2[8];
  #pragma unroll
  for (int q = 0; q < 8; q++){ s1[q] = 0.f; s2[q] = 0.f; }
  #pragma unroll
  for (int it = 0; it < 4; it++){
    size_t row = (size_t)bid * 64 + it * 16 + rl;
    short8 h = *reinterpret_cast<const short8*>(y10 + row * 96 + c8 * 8);
    #pragma unroll
    for (int q = 0; q < 8; q++){
      float v = bf2f((u16)h[q]);
      s1[q] += v; s2[q] += v * v;
    }
  }
  #pragma unroll
  for (int q = 0; q < 8; q++){
    atomicAdd(&ls[c8 * 8 + q], s1[q]);
    atomicAdd(&lq[c8 * 8 + q], s2[q]);
  }
  __syncthreads();
  if (tid < 96){ atomicAdd(&stats[tid], ls[tid]); atomicAdd(&stats[1056 + tid], lq[tid]); }
}

// ---------------- out0 = data0 + up(relu(bn(y10))); p0 = pool(data0); p00 = pool(p0) ----------------
// LINEAR mapping (R13): wave = 1024B contiguous nt loads/stores. AT HBM RATE (68.3us measured).
__global__ __launch_bounds__(256) void k_out0(const float* __restrict__ d0, const u16* __restrict__ y10,
                                              const float* __restrict__ stats,
                                              const float* __restrict__ g10, const float* __restrict__ b10,
                                              float* __restrict__ out0, u16* __restrict__ p0, u16* __restrict__ p00){
  __shared__ float yv[8][96];
  __shared__ float sd[64][100];
  __shared__ float sp[8][96];
  int tid = threadIdx.x, gp = blockIdx.x;

  if (tid < 192){
    int p = tid / 24, c4 = tid - p * 24;
    u16x4 yb = *reinterpret_cast<const u16x4*>(y10 + ((size_t)gp * 8 + p) * 96 + c4 * 4);
    f4 o;
    #pragma unroll
    for (int q = 0; q < 4; q++){
      int c = c4 * 4 + q;
      float m = stats[c] * (1.f / 65536.f);
      float vv = stats[1056 + c] * (1.f / 65536.f) - m * m;
      float a = g10[c] * rsqrtf(vv + 1e-5f);
      float cc = b10[c] - m * a;
      o[q] = fmaxf(bf2f((u16)yb[q]) * a + cc, 0.f);
    }
    *reinterpret_cast<f4*>(&yv[p][c4 * 4]) = o;
  }
  __syncthreads();

  const float* dsrc = d0 + (size_t)gp * 6144;
  float* ddst = out0 + (size_t)gp * 6144;
  f4 v[6];
  #pragma unroll
  for (int i = 0; i < 6; i++) v[i] = nt_load4(dsrc + (i * 256 + tid) * 4);
  #pragma unroll
  for (int i = 0; i < 6; i++){
    int idx = i * 256 + tid;
    int row = idx / 24, c4 = idx - row * 24;
    f4 y = *reinterpret_cast<f4*>(&yv[row >> 3][c4 * 4]);
    f4 o;
    #pragma unroll
    for (int q = 0; q < 4; q++) o[q] = v[i][q] + y[q];
    nt_store4(ddst + idx * 4, o);
    *reinterpret_cast<f4*>(&sd[row][c4 * 4]) = v[i];
  }
  __syncthreads();

  if (tid < 192){
    int p = tid / 24, c4 = tid - p * 24;
    f4 m = *reinterpret_cast<f4*>(&sd[p * 8][c4 * 4]);
    #pragma unroll
    for (int r = 1; r < 8; r++){
      f4 x = *reinterpret_cast<f4*>(&sd[p * 8 + r][c4 * 4]);
      #pragma unroll
      for (int q = 0; q < 4; q++) m[q] = fmaxf(m[q], x[q]);
    }
    u16x4 h;
    #pragma unroll
    for (int q = 0; q < 4; q++) h[q] = f2bf(m[q]);
    *reinterpret_cast<u16x4*>(p0 + ((size_t)gp * 8 + p) * 96 + c4 * 4) = h;
    *reinterpret_cast<f4*>(&sp[p][c4 * 4]) = m;
  }
  __syncthreads();
  if (tid < 24){
    f4 m = *reinterpret_cast<f4*>(&sp[0][tid * 4]);
    #pragma unroll
    for (int pp = 1; pp < 8; pp++){
      f4 x = *reinterpret_cast<f4*>(&sp[pp][tid * 4]);
      #pragma unroll
      for (int q = 0; q < 4; q++) m[q] = fmaxf(m[q], x[q]);
    }
    u16x4 h;
    #pragma unroll
    for (int q = 0; q < 4; q++) h[q] = f2bf(m[q]);
    *reinterpret_cast<u16x4*>(p00 + (size_t)gp * 96 + tid * 4) = h;
  }
}

// ---------------- stats-only GEMM body: shfl pre-reduce (LDS atomics /4, contention 16->4 way) ----------------
template<int Ci, int Co>
__device__ __forceinline__ void stats_body(const u16* __restrict__ x, const u16* __restrict__ wT,
                                           float* __restrict__ sum, float* __restrict__ sq,
                                           int bid, float* ls, float* lq){
  int tid = threadIdx.x;
  for (int t = tid; t < Co; t += 256){ ls[t] = 0.f; lq[t] = 0.f; }
  __syncthreads();
  int lane = tid & 63, wave = tid >> 6;
  int arow = bid * 64 + wave * 16 + (lane & 15);
  int k0 = (lane >> 4) * 8;
  constexpr int KS = Ci / 32;
  short8 af[KS];
  const u16* xr = x + (size_t)arow * Ci + k0;
  #pragma unroll
  for (int s = 0; s < KS; s++) af[s] = *reinterpret_cast<const short8*>(xr + s * 32);
  int colb = lane & 15;
  #pragma unroll 4
  for (int j = 0; j < Co / 16; j++){
    int col = j * 16 + colb;
    f4 acc = {0.f, 0.f, 0.f, 0.f};
    const u16* wr = wT + (size_t)col * Ci + k0;
    #pragma unroll
    for (int s = 0; s < KS; s++)
      acc = __builtin_amdgcn_mfma_f32_16x16x32_bf16(af[s], *reinterpret_cast<const short8*>(wr + s * 32), acc, 0, 0, 0);
    float s1 = acc[0] + acc[1] + acc[2] + acc[3];
    float s2 = acc[0]*acc[0] + acc[1]*acc[1] + acc[2]*acc[2] + acc[3]*acc[3];
    // lanes {l, l^16, l^32, l^48} hold different row-groups of the SAME col: combine in-register
    s1 += __shfl_xor(s1, 16); s1 += __shfl_xor(s1, 32);
    s2 += __shfl_xor(s2, 16); s2 += __shfl_xor(s2, 32);
    if ((lane >> 4) == 0){
      atomicAdd(&ls[col], s1);
      atomicAdd(&lq[col], s2);
    }
  }
  __syncthreads();
  for (int t = tid; t < Co; t += 256){ atomicAdd(&sum[t], ls[t]); atomicAdd(&sq[t], lq[t]); }
}

// blocks [0,1024): stats01(p0)  [1024,1152): stats02(p00)  [1152,1280): stats12(p1)
__global__ __launch_bounds__(256) void k_statsAll(const u16* __restrict__ p0, const u16* __restrict__ p00,
                                                  const u16* __restrict__ p1,
                                                  const u16* __restrict__ wT01, const u16* __restrict__ wT02,
                                                  const u16* __restrict__ wT12, float* __restrict__ stats){
  __shared__ float ls[384], lq[384];
  int bid = blockIdx.x;
  if (bid < 1024)      stats_body<96, 192>(p0,  wT01, stats + 96,  stats + 1056 + 96,  bid,        ls, lq);
  else if (bid < 1152) stats_body<96, 384>(p00, wT02, stats + 288, stats + 1056 + 288, bid - 1024, ls, lq);
  else                 stats_body<192,384>(p1,  wT12, stats + 672, stats + 1056 + 672, bid - 1152, ls, lq);
}

// ---------------- merged epilogue: blocks [0,1024) = out1, [1024,1280) = out2 ----------------
union ShOut {
  struct { float aL[192], cL[192], so[64 * 196]; } o1;                    // 51712
  struct { float a2[384], c2[384], a1[384], c1[384], so2[32 * 392]; } o2; // 56320
};

__global__ __launch_bounds__(256) void k_outfinal(const u16* __restrict__ p0, const u16* __restrict__ wT01,
                                                  const float* __restrict__ d1,
                                                  const u16* __restrict__ p00, const u16* __restrict__ p1,
                                                  const u16* __restrict__ wT02, const u16* __restrict__ wT12,
                                                  const float* __restrict__ stats,
                                                  const float* __restrict__ g01, const float* __restrict__ b01,
                                                  const float* __restrict__ g02, const float* __restrict__ b02,
                                                  const float* __restrict__ g12, const float* __restrict__ b12,
                                                  float* __restrict__ out1, float* __restrict__ out2){
  __shared__ ShOut sh;
  int tid = threadIdx.x;
  if (blockIdx.x < 1024){
    int bid = blockIdx.x;
    if (tid < 192){
      float m = stats[96 + tid] * (1.f / 65536.f);
      float v = stats[1056 + 96 + tid] * (1.f / 65536.f) - m * m;
      float a = g01[tid] * rsqrtf(v + 1e-5f);
      sh.o1.aL[tid] = a; sh.o1.cL[tid] = b01[tid] - m * a;
    }
    __syncthreads();
    int lane = tid & 63, wave = tid >> 6;
    int colb = lane & 15;
    int k0 = (lane >> 4) * 8, rgrp = (lane >> 4) * 4;
    int rowl = wave * 16 + colb;
    short8 xf[3];
    const u16* xr = p0 + ((size_t)bid * 64 + rowl) * 96 + k0;
    #pragma unroll
    for (int s = 0; s < 3; s++) xf[s] = *reinterpret_cast<const short8*>(xr + s * 32);
    #pragma unroll 4
    for (int j = 0; j < 12; j++){
      int ch0 = j * 16 + rgrp;
      f4 acc = {0.f, 0.f, 0.f, 0.f};
      const u16* wr = wT01 + (size_t)(j * 16 + colb) * 96 + k0;
      #pragma unroll
      for (int s = 0; s < 3; s++)
        acc = __builtin_amdgcn_mfma_f32_16x16x32_bf16(*reinterpret_cast<const short8*>(wr + s * 32), xf[s], acc, 0, 0, 0);
      f4 o;
      #pragma unroll
      for (int r = 0; r < 4; r++){
        int ch = ch0 + r;
        o[r] = fmaxf(acc[r] * sh.o1.aL[ch] + sh.o1.cL[ch], 0.f);
      }
      *reinterpret_cast<f4*>(&sh.o1.so[rowl * 196 + ch0]) = o;
    }
    __syncthreads();
    const float* d1b = d1 + (size_t)bid * 64 * 192;
    float* o1b = out1 + (size_t)bid * 64 * 192;
    #pragma unroll
    for (int i = 0; i < 12; i++){
      int idx = i * 256 + tid;
      int rl = idx / 48, c4i = idx % 48;
      f4 y = *reinterpret_cast<f4*>(&sh.o1.so[rl * 196 + c4i * 4]);
      int off = rl * 192 + c4i * 4;
      f4 g = nt_load4(d1b + off);
      f4 o;
      #pragma unroll
      for (int q = 0; q < 4; q++) o[q] = y[q] + g[q];
      nt_store4(o1b + off, o);
    }
  } else {
    int bid = blockIdx.x - 1024;
    for (int t = tid; t < 384; t += 256){
      float m = stats[288 + t] * (1.f / 8192.f);
      float v = stats[1056 + 288 + t] * (1.f / 8192.f) - m * m;
      float a = g02[t] * rsqrtf(v + 1e-5f);
      sh.o2.a2[t] = a; sh.o2.c2[t] = b02[t] - m * a;
      m = stats[672 + t] * (1.f / 8192.f);
      v = stats[1056 + 672 + t] * (1.f / 8192.f) - m * m;
      a = g12[t] * rsqrtf(v + 1e-5f);
      sh.o2.a1[t] = a; sh.o2.c1[t] = b12[t] - m * a;
    }
    __syncthreads();
    int lane = tid & 63, wave = tid >> 6;
    int wr2 = wave >> 1, wc = wave & 1;
    int colb = lane & 15;
    int k0 = (lane >> 4) * 8, rgrp = (lane >> 4) * 4;
    int rowl = wr2 * 16 + colb;
    size_t arow = (size_t)bid * 32 + rowl;
    short8 xA[3], xB[6];
    #pragma unroll
    for (int s = 0; s < 3; s++) xA[s] = *reinterpret_cast<const short8*>(p00 + arow * 96 + k0 + s * 32);
    #pragma unroll
    for (int s = 0; s < 6; s++) xB[s] = *reinterpret_cast<const short8*>(p1 + arow * 192 + k0 + s * 32);
    #pragma unroll 2
    for (int j = 0; j < 12; j++){
      int ch0 = wc * 192 + j * 16 + rgrp;
      int wrow = wc * 192 + j * 16 + colb;
      f4 u = {0.f, 0.f, 0.f, 0.f}, w = {0.f, 0.f, 0.f, 0.f};
      const u16* wra = wT02 + (size_t)wrow * 96 + k0;
      #pragma unroll
      for (int s = 0; s < 3; s++)
        u = __builtin_amdgcn_mfma_f32_16x16x32_bf16(*reinterpret_cast<const short8*>(wra + s * 32), xA[s], u, 0, 0, 0);
      const u16* wrb = wT12 + (size_t)wrow * 192 + k0;
      #pragma unroll
      for (int s = 0; s < 6; s++)
        w = __builtin_amdgcn_mfma_f32_16x16x32_bf16(*reinterpret_cast<const short8*>(wrb + s * 32), xB[s], w, 0, 0, 0);
      f4 o;
      #pragma unroll
      for (int r = 0; r < 4; r++){
        int ch = ch0 + r;
        o[r] = fmaxf(u[r] * sh.o2.a2[ch] + sh.o2.c2[ch], 0.f) + fmaxf(w[r] * sh.o2.a1[ch] + sh.o2.c1[ch], 0.f);
      }
      *reinterpret_cast<f4*>(&sh.o2.so2[rowl * 392 + ch0]) = o;
    }
    __syncthreads();
    #pragma unroll
    for (int i = 0; i < 12; i++){
      int idx = i * 256 + tid;
      int rl = idx / 96, c4i = idx % 96;
      f4 v = *reinterpret_cast<f4*>(&sh.o2.so2[rl * 392 + c4i * 4]);
      nt_store4(out2 + ((size_t)bid * 32 + rl) * 384 + c4i * 4, v);
    }
  }
}

extern "C" void kernel_launch(void* const* d_in, const int* in_sizes, int n_in,
                              void* d_out, int out_size, void* d_ws, size_t ws_size,
                              hipStream_t stream){
  const float* data0 = (const float*)d_in[0];
  const float* data1 = (const float*)d_in[1];
  const float* w01 = (const float*)d_in[2];
  const float* g01 = (const float*)d_in[3];
  const float* b01 = (const float*)d_in[4];
  const float* w02 = (const float*)d_in[5];
  const float* g02 = (const float*)d_in[6];
  const float* b02 = (const float*)d_in[7];
  const float* w10 = (const float*)d_in[8];
  const float* g10 = (const float*)d_in[9];
  const float* b10 = (const float*)d_in[10];
  const float* w12 = (const float*)d_in[11];
  const float* g12 = (const float*)d_in[12];
  const float* b12 = (const float*)d_in[13];

  float* out0 = (float*)d_out;                 // [524288, 96]
  float* out1 = out0 + (size_t)CN6 * 96;       // [65536, 192]
  float* out2 = out1 + (size_t)CN5 * 192;      // [8192, 384]

  char* ws = (char*)d_ws;
  u16* p1   = (u16*)(ws + 0);                  //  3145728 B
  u16* p0   = (u16*)(ws + 3145728);            // 12582912
  u16* p00  = (u16*)(ws + 15728640);           //  1572864
  u16* y10  = (u16*)(ws + 17301504);           // 12582912
  u16* wT10 = (u16*)(ws + 29884416);           //    36864
  u16* wT01 = (u16*)(ws + 29921280);           //    36864
  u16* wT02 = (u16*)(ws + 29958144);           //    73728
  u16* wT12 = (u16*)(ws + 30031872);           //   147456
  float* stats = (float*)(ws + 30179328);      //     8448 (2112 f32: sum | sq)

  k_prep<<<576, 256, 0, stream>>>(w10, w01, w02, w12, wT10, wT01, wT02, wT12, stats);
  k_gemm10p<<<1024, 256, 0, stream>>>(data1, wT10, y10, p1);
  k_stats10<<<1024, 192, 0, stream>>>(y10, stats);
  k_out0<<<8192, 256, 0, stream>>>(data0, y10, stats, g10, b10, out0, p0, p00);
  k_statsAll<<<1280, 256, 0, stream>>>(p0, p00, p1, wT01, wT02, wT12, stats);
  k_outfinal<<<1280, 256, 0, stream>>>(p0, wT01, data1, p00, p1, wT02, wT12, stats,
                                       g01, b01, g02, b02, g12, b12, out1, out2);
}

// Round 18
// 212.894 us; speedup vs baseline: 1.3250x; 1.1329x over previous
//
#include <hip/hip_runtime.h>

typedef unsigned short u16;
typedef __attribute__((ext_vector_type(8))) short short8;
typedef __attribute__((ext_vector_type(4))) float f4;
typedef __attribute__((ext_vector_type(4))) unsigned short u16x4;

#define CN6 524288
#define CN5 65536
#define CN4 8192

__device__ inline u16 f2bf(float f){
  unsigned u = __float_as_uint(f);
  return (u16)((u + 0x7FFFu + ((u >> 16) & 1u)) >> 16);
}
__device__ inline float bf2f(u16 h){ return __uint_as_float(((unsigned)h) << 16); }

__device__ inline f4 nt_load4(const float* p){
  return __builtin_nontemporal_load(reinterpret_cast<const f4*>(p));
}
__device__ inline void nt_store4(float* p, f4 v){
  __builtin_nontemporal_store(v, reinterpret_cast<f4*>(p));
}

// stats layout: sum = stats[0..1056), sq = stats[1056..2112)
// channel offsets: conv10: 0  conv01: 96  conv02: 288  conv12: 672

// ---------------- prep: all 4 weight transposes (f32->bf16) + zero stats ----------------
__global__ __launch_bounds__(256) void k_prep(const float* __restrict__ w10, const float* __restrict__ w01,
                                              const float* __restrict__ w02, const float* __restrict__ w12,
                                              u16* __restrict__ wT10, u16* __restrict__ wT01,
                                              u16* __restrict__ wT02, u16* __restrict__ wT12,
                                              float* __restrict__ stats){
  int i = blockIdx.x * 256 + threadIdx.x;
  if (i < 2112) stats[i] = 0.f;
  if (i < 18432){ int j = i / 192, k = i - j * 192; wT10[i] = f2bf(w10[k * 96 + j]); }
  else if (i < 36864){ int e = i - 18432; int j = e / 96, k = e - j * 96; wT01[e] = f2bf(w01[k * 192 + j]); }
  else if (i < 73728){ int e = i - 36864; int j = e / 96, k = e - j * 96; wT02[e] = f2bf(w02[k * 384 + j]); }
  else if (i < 147456){ int e = i - 73728; int j = e / 192, k = e - j * 192; wT12[e] = f2bf(w12[k * 384 + j]); }
}

// ---------------- fused: data1 f32 -> bf16 LDS tile (32 rows), pool -> p1, GEMM y10 ----------------
// 2048 blocks x 32 rows: LDS 12.8KB -> high blocks/CU for phase overlap.
// Waves: w&1 = row-group (16 rows), w>>1 = col-half (3 j-tiles of 16 ch).
__global__ __launch_bounds__(256) void k_gemm10p(const float* __restrict__ d1, const u16* __restrict__ wT10,
                                                 u16* __restrict__ y10, u16* __restrict__ p1){
  __shared__ u16 sm[32 * 200];       // 32 rows x 192 bf16, padded to 200
  int tid = threadIdx.x, bid = blockIdx.x;

  if (tid < 96){
    int p = tid / 24, c8 = tid - p * 24;      // 4 parents x 24 8-ch chunks
    f4 v0[8], v1[8];
    #pragma unroll
    for (int r = 0; r < 8; r++){
      const float* src = d1 + ((size_t)bid * 32 + p * 8 + r) * 192 + c8 * 8;
      v0[r] = *reinterpret_cast<const f4*>(src);
      v1[r] = *reinterpret_cast<const f4*>(src + 4);
    }
    float mx[8];
    #pragma unroll
    for (int q = 0; q < 4; q++){ mx[q] = v0[0][q]; mx[4 + q] = v1[0][q]; }
    #pragma unroll
    for (int r = 0; r < 8; r++){
      short8 h;
      #pragma unroll
      for (int q = 0; q < 4; q++){
        h[q]     = (short)f2bf(v0[r][q]);
        h[4 + q] = (short)f2bf(v1[r][q]);
        if (r){ mx[q] = fmaxf(mx[q], v0[r][q]); mx[4 + q] = fmaxf(mx[4 + q], v1[r][q]); }
      }
      *reinterpret_cast<short8*>(&sm[(p * 8 + r) * 200 + c8 * 8]) = h;
    }
    short8 hp;
    #pragma unroll
    for (int q = 0; q < 8; q++) hp[q] = (short)f2bf(mx[q]);
    *reinterpret_cast<short8*>(p1 + ((size_t)bid * 4 + p) * 192 + c8 * 8) = hp;
  }
  __syncthreads();

  int lane = tid & 63, wave = tid >> 6;
  int colb = lane & 15;
  int k0 = (lane >> 4) * 8, rgrp = (lane >> 4) * 4;
  int arowl = (wave & 1) * 16 + colb;        // row within 32-row tile
  int jbase = (wave >> 1) * 3;               // col-half: 3 j-tiles
  short8 xf[6];
  #pragma unroll
  for (int s = 0; s < 6; s++) xf[s] = *reinterpret_cast<short8*>(&sm[arowl * 200 + s * 32 + k0]);

  size_t xrow = (size_t)bid * 32 + arowl;
  #pragma unroll
  for (int jj = 0; jj < 3; jj++){
    int j = jbase + jj;
    f4 acc = {0.f, 0.f, 0.f, 0.f};
    const u16* wr = wT10 + (size_t)(j * 16 + colb) * 192 + k0;
    #pragma unroll
    for (int s = 0; s < 6; s++)
      acc = __builtin_amdgcn_mfma_f32_16x16x32_bf16(*reinterpret_cast<const short8*>(wr + s * 32), xf[s], acc, 0, 0, 0);
    u16x4 h;
    #pragma unroll
    for (int r = 0; r < 4; r++) h[r] = f2bf(acc[r]);
    *reinterpret_cast<u16x4*>(y10 + xrow * 96 + j * 16 + rgrp) = h;
  }
}

// ---------------- stats for conv10: column sum/sumsq over y10 (bf16, L2-hot) ----------------
__global__ __launch_bounds__(192) void k_stats10(const u16* __restrict__ y10, float* __restrict__ stats){
  __shared__ float ls[96], lq[96];
  int tid = threadIdx.x, bid = blockIdx.x;
  if (tid < 96){ ls[tid] = 0.f; lq[tid] = 0.f; }
  __syncthreads();
  int c8 = tid % 12, rl = tid / 12;          // 12 8-ch chunks x 16 rows
  float s1[8], s2[8];
  #pragma unroll
  for (int q = 0; q < 8; q++){ s1[q] = 0.f; s2[q] = 0.f; }
  for (int it = 0; it < 32; it++){
    size_t row = (size_t)bid * 512 + it * 16 + rl;
    short8 h = *reinterpret_cast<const short8*>(y10 + row * 96 + c8 * 8);
    #pragma unroll
    for (int q = 0; q < 8; q++){
      float v = bf2f((u16)h[q]);
      s1[q] += v; s2[q] += v * v;
    }
  }
  #pragma unroll
  for (int q = 0; q < 8; q++){
    atomicAdd(&ls[c8 * 8 + q], s1[q]);
    atomicAdd(&lq[c8 * 8 + q], s2[q]);
  }
  __syncthreads();
  if (tid < 96){ atomicAdd(&stats[tid], ls[tid]); atomicAdd(&stats[1056 + tid], lq[tid]); }
}

// ---------------- out0 = data0 + up(relu(bn(y10))); p0 = pool(data0); p00 = pool(p0) ----------------
// LINEAR mapping (R13): wave = 1024B contiguous nt loads/stores. AT HBM RATE (68.3us measured).
__global__ __launch_bounds__(256) void k_out0(const float* __restrict__ d0, const u16* __restrict__ y10,
                                              const float* __restrict__ stats,
                                              const float* __restrict__ g10, const float* __restrict__ b10,
                                              float* __restrict__ out0, u16* __restrict__ p0, u16* __restrict__ p00){
  __shared__ float yv[8][96];
  __shared__ float sd[64][100];
  __shared__ float sp[8][96];
  int tid = threadIdx.x, gp = blockIdx.x;

  if (tid < 192){
    int p = tid / 24, c4 = tid - p * 24;
    u16x4 yb = *reinterpret_cast<const u16x4*>(y10 + ((size_t)gp * 8 + p) * 96 + c4 * 4);
    f4 o;
    #pragma unroll
    for (int q = 0; q < 4; q++){
      int c = c4 * 4 + q;
      float m = stats[c] * (1.f / 65536.f);
      float vv = stats[1056 + c] * (1.f / 65536.f) - m * m;
      float a = g10[c] * rsqrtf(vv + 1e-5f);
      float cc = b10[c] - m * a;
      o[q] = fmaxf(bf2f((u16)yb[q]) * a + cc, 0.f);
    }
    *reinterpret_cast<f4*>(&yv[p][c4 * 4]) = o;
  }
  __syncthreads();

  const float* dsrc = d0 + (size_t)gp * 6144;
  float* ddst = out0 + (size_t)gp * 6144;
  f4 v[6];
  #pragma unroll
  for (int i = 0; i < 6; i++) v[i] = nt_load4(dsrc + (i * 256 + tid) * 4);
  #pragma unroll
  for (int i = 0; i < 6; i++){
    int idx = i * 256 + tid;
    int row = idx / 24, c4 = idx - row * 24;
    f4 y = *reinterpret_cast<f4*>(&yv[row >> 3][c4 * 4]);
    f4 o;
    #pragma unroll
    for (int q = 0; q < 4; q++) o[q] = v[i][q] + y[q];
    nt_store4(ddst + idx * 4, o);
    *reinterpret_cast<f4*>(&sd[row][c4 * 4]) = v[i];
  }
  __syncthreads();

  if (tid < 192){
    int p = tid / 24, c4 = tid - p * 24;
    f4 m = *reinterpret_cast<f4*>(&sd[p * 8][c4 * 4]);
    #pragma unroll
    for (int r = 1; r < 8; r++){
      f4 x = *reinterpret_cast<f4*>(&sd[p * 8 + r][c4 * 4]);
      #pragma unroll
      for (int q = 0; q < 4; q++) m[q] = fmaxf(m[q], x[q]);
    }
    u16x4 h;
    #pragma unroll
    for (int q = 0; q < 4; q++) h[q] = f2bf(m[q]);
    *reinterpret_cast<u16x4*>(p0 + ((size_t)gp * 8 + p) * 96 + c4 * 4) = h;
    *reinterpret_cast<f4*>(&sp[p][c4 * 4]) = m;
  }
  __syncthreads();
  if (tid < 24){
    f4 m = *reinterpret_cast<f4*>(&sp[0][tid * 4]);
    #pragma unroll
    for (int pp = 1; pp < 8; pp++){
      f4 x = *reinterpret_cast<f4*>(&sp[pp][tid * 4]);
      #pragma unroll
      for (int q = 0; q < 4; q++) m[q] = fmaxf(m[q], x[q]);
    }
    u16x4 h;
    #pragma unroll
    for (int q = 0; q < 4; q++) h[q] = f2bf(m[q]);
    *reinterpret_cast<u16x4*>(p00 + (size_t)gp * 96 + tid * 4) = h;
  }
}

// ---------------- stats-only GEMM body (no y write) — R13 version (no shfl) ----------------
template<int Ci, int Co>
__device__ __forceinline__ void stats_body(const u16* __restrict__ x, const u16* __restrict__ wT,
                                           float* __restrict__ sum, float* __restrict__ sq,
                                           int bid, float* ls, float* lq){
  int tid = threadIdx.x;
  for (int t = tid; t < Co; t += 256){ ls[t] = 0.f; lq[t] = 0.f; }
  __syncthreads();
  int lane = tid & 63, wave = tid >> 6;
  int arow = bid * 64 + wave * 16 + (lane & 15);
  int k0 = (lane >> 4) * 8;
  constexpr int KS = Ci / 32;
  short8 af[KS];
  const u16* xr = x + (size_t)arow * Ci + k0;
  #pragma unroll
  for (int s = 0; s < KS; s++) af[s] = *reinterpret_cast<const short8*>(xr + s * 32);
  int colb = lane & 15;
  #pragma unroll 4
  for (int j = 0; j < Co / 16; j++){
    int col = j * 16 + colb;
    f4 acc = {0.f, 0.f, 0.f, 0.f};
    const u16* wr = wT + (size_t)col * Ci + k0;
    #pragma unroll
    for (int s = 0; s < KS; s++)
      acc = __builtin_amdgcn_mfma_f32_16x16x32_bf16(af[s], *reinterpret_cast<const short8*>(wr + s * 32), acc, 0, 0, 0);
    float s1 = acc[0] + acc[1] + acc[2] + acc[3];
    float s2 = acc[0]*acc[0] + acc[1]*acc[1] + acc[2]*acc[2] + acc[3]*acc[3];
    atomicAdd(&ls[col], s1);
    atomicAdd(&lq[col], s2);
  }
  __syncthreads();
  for (int t = tid; t < Co; t += 256){ atomicAdd(&sum[t], ls[t]); atomicAdd(&sq[t], lq[t]); }
}

// blocks [0,1024): stats01(p0)  [1024,1152): stats02(p00)  [1152,1280): stats12(p1)
__global__ __launch_bounds__(256) void k_statsAll(const u16* __restrict__ p0, const u16* __restrict__ p00,
                                                  const u16* __restrict__ p1,
                                                  const u16* __restrict__ wT01, const u16* __restrict__ wT02,
                                                  const u16* __restrict__ wT12, float* __restrict__ stats){
  __shared__ float ls[384], lq[384];
  int bid = blockIdx.x;
  if (bid < 1024)      stats_body<96, 192>(p0,  wT01, stats + 96,  stats + 1056 + 96,  bid,        ls, lq);
  else if (bid < 1152) stats_body<96, 384>(p00, wT02, stats + 288, stats + 1056 + 288, bid - 1024, ls, lq);
  else                 stats_body<192,384>(p1,  wT12, stats + 672, stats + 1056 + 672, bid - 1152, ls, lq);
}

// ---------------- out1 = relu(bn(p0 @ w01)) + data1 (32-row tiles, 2048 blocks) ----------------
// Waves: w&1 = row-group, w>>1 = j-half (6 j-tiles each). LDS 26.5KB -> ~5 blocks/CU.
__global__ __launch_bounds__(256) void k_out1(const u16* __restrict__ p0, const u16* __restrict__ wT01,
                                              const float* __restrict__ d1, const float* __restrict__ stats,
                                              const float* __restrict__ g01, const float* __restrict__ b01,
                                              float* __restrict__ out1){
  __shared__ float aL[192], cL[192];
  __shared__ float so[32 * 196];     // 32 rows x 192 f32, stride 196
  int tid = threadIdx.x, bid = blockIdx.x;
  if (tid < 192){
    float m = stats[96 + tid] * (1.f / 65536.f);
    float v = stats[1056 + 96 + tid] * (1.f / 65536.f) - m * m;
    float a = g01[tid] * rsqrtf(v + 1e-5f);
    aL[tid] = a; cL[tid] = b01[tid] - m * a;
  }
  __syncthreads();
  int lane = tid & 63, wave = tid >> 6;
  int colb = lane & 15;
  int k0 = (lane >> 4) * 8, rgrp = (lane >> 4) * 4;
  int rowl = (wave & 1) * 16 + colb;         // row within 32-row tile
  int jbase = (wave >> 1) * 6;               // j-half
  short8 xf[3];
  const u16* xr = p0 + ((size_t)bid * 32 + rowl) * 96 + k0;
  #pragma unroll
  for (int s = 0; s < 3; s++) xf[s] = *reinterpret_cast<const short8*>(xr + s * 32);
  #pragma unroll
  for (int jj = 0; jj < 6; jj++){
    int j = jbase + jj;
    int ch0 = j * 16 + rgrp;
    f4 acc = {0.f, 0.f, 0.f, 0.f};
    const u16* wr = wT01 + (size_t)(j * 16 + colb) * 96 + k0;
    #pragma unroll
    for (int s = 0; s < 3; s++)
      acc = __builtin_amdgcn_mfma_f32_16x16x32_bf16(*reinterpret_cast<const short8*>(wr + s * 32), xf[s], acc, 0, 0, 0);
    f4 o;
    #pragma unroll
    for (int r = 0; r < 4; r++){
      int ch = ch0 + r;
      o[r] = fmaxf(acc[r] * aL[ch] + cL[ch], 0.f);
    }
    *reinterpret_cast<f4*>(&so[rowl * 196 + ch0]) = o;
  }
  __syncthreads();
  const float* d1b = d1 + (size_t)bid * 32 * 192;
  float* o1b = out1 + (size_t)bid * 32 * 192;
  #pragma unroll
  for (int i = 0; i < 6; i++){
    int idx = i * 256 + tid;
    int rl = idx / 48, c4i = idx % 48;
    f4 y = *reinterpret_cast<f4*>(&so[rl * 196 + c4i * 4]);
    int off = rl * 192 + c4i * 4;
    f4 g = nt_load4(d1b + off);
    f4 o;
    #pragma unroll
    for (int q = 0; q < 4; q++) o[q] = y[q] + g[q];
    nt_store4(o1b + off, o);
  }
}

// ---------------- out2 = relu(bn(p00 @ w02)) + relu(bn(p1 @ w12)) ----------------
__global__ __launch_bounds__(256) void k_out2(const u16* __restrict__ p00, const u16* __restrict__ p1,
                                              const u16* __restrict__ wT02, const u16* __restrict__ wT12,
                                              const float* __restrict__ stats,
                                              const float* __restrict__ g02, const float* __restrict__ b02,
                                              const float* __restrict__ g12, const float* __restrict__ b12,
                                              float* __restrict__ out2){
  __shared__ float a2[384], c2[384], a1[384], c1[384];
  __shared__ float so[32 * 392];     // 32 rows x 384 f32, stride 392
  int tid = threadIdx.x, bid = blockIdx.x;
  for (int t = tid; t < 384; t += 256){
    float m = stats[288 + t] * (1.f / 8192.f);
    float v = stats[1056 + 288 + t] * (1.f / 8192.f) - m * m;
    float a = g02[t] * rsqrtf(v + 1e-5f);
    a2[t] = a; c2[t] = b02[t] - m * a;
    m = stats[672 + t] * (1.f / 8192.f);
    v = stats[1056 + 672 + t] * (1.f / 8192.f) - m * m;
    a = g12[t] * rsqrtf(v + 1e-5f);
    a1[t] = a; c1[t] = b12[t] - m * a;
  }
  __syncthreads();
  int lane = tid & 63, wave = tid >> 6;
  int wr2 = wave >> 1, wc = wave & 1;
  int colb = lane & 15;
  int k0 = (lane >> 4) * 8, rgrp = (lane >> 4) * 4;
  int rowl = wr2 * 16 + colb;
  size_t arow = (size_t)bid * 32 + rowl;
  short8 xA[3], xB[6];
  #pragma unroll
  for (int s = 0; s < 3; s++) xA[s] = *reinterpret_cast<const short8*>(p00 + arow * 96 + k0 + s * 32);
  #pragma unroll
  for (int s = 0; s < 6; s++) xB[s] = *reinterpret_cast<const short8*>(p1 + arow * 192 + k0 + s * 32);
  #pragma unroll 2
  for (int j = 0; j < 12; j++){
    int ch0 = wc * 192 + j * 16 + rgrp;
    int wrow = wc * 192 + j * 16 + colb;
    f4 u = {0.f, 0.f, 0.f, 0.f}, w = {0.f, 0.f, 0.f, 0.f};
    const u16* wra = wT02 + (size_t)wrow * 96 + k0;
    #pragma unroll
    for (int s = 0; s < 3; s++)
      u = __builtin_amdgcn_mfma_f32_16x16x32_bf16(*reinterpret_cast<const short8*>(wra + s * 32), xA[s], u, 0, 0, 0);
    const u16* wrb = wT12 + (size_t)wrow * 192 + k0;
    #pragma unroll
    for (int s = 0; s < 6; s++)
      w = __builtin_amdgcn_mfma_f32_16x16x32_bf16(*reinterpret_cast<const short8*>(wrb + s * 32), xB[s], w, 0, 0, 0);
    f4 o;
    #pragma unroll
    for (int r = 0; r < 4; r++){
      int ch = ch0 + r;
      o[r] = fmaxf(u[r] * a2[ch] + c2[ch], 0.f) + fmaxf(w[r] * a1[ch] + c1[ch], 0.f);
    }
    *reinterpret_cast<f4*>(&so[rowl * 392 + ch0]) = o;
  }
  __syncthreads();
  #pragma unroll
  for (int i = 0; i < 12; i++){
    int idx = i * 256 + tid;
    int rl = idx / 96, c4i = idx % 96;
    f4 v = *reinterpret_cast<f4*>(&so[rl * 392 + c4i * 4]);
    nt_store4(out2 + ((size_t)bid * 32 + rl) * 384 + c4i * 4, v);
  }
}

extern "C" void kernel_launch(void* const* d_in, const int* in_sizes, int n_in,
                              void* d_out, int out_size, void* d_ws, size_t ws_size,
                              hipStream_t stream){
  const float* data0 = (const float*)d_in[0];
  const float* data1 = (const float*)d_in[1];
  const float* w01 = (const float*)d_in[2];
  const float* g01 = (const float*)d_in[3];
  const float* b01 = (const float*)d_in[4];
  const float* w02 = (const float*)d_in[5];
  const float* g02 = (const float*)d_in[6];
  const float* b02 = (const float*)d_in[7];
  const float* w10 = (const float*)d_in[8];
  const float* g10 = (const float*)d_in[9];
  const float* b10 = (const float*)d_in[10];
  const float* w12 = (const float*)d_in[11];
  const float* g12 = (const float*)d_in[12];
  const float* b12 = (const float*)d_in[13];

  float* out0 = (float*)d_out;                 // [524288, 96]
  float* out1 = out0 + (size_t)CN6 * 96;       // [65536, 192]
  float* out2 = out1 + (size_t)CN5 * 192;      // [8192, 384]

  char* ws = (char*)d_ws;
  u16* p1   = (u16*)(ws + 0);                  //  3145728 B
  u16* p0   = (u16*)(ws + 3145728);            // 12582912
  u16* p00  = (u16*)(ws + 15728640);           //  1572864
  u16* y10  = (u16*)(ws + 17301504);           // 12582912
  u16* wT10 = (u16*)(ws + 29884416);           //    36864
  u16* wT01 = (u16*)(ws + 29921280);           //    36864
  u16* wT02 = (u16*)(ws + 29958144);           //    73728
  u16* wT12 = (u16*)(ws + 30031872);           //   147456
  float* stats = (float*)(ws + 30179328);      //     8448 (2112 f32: sum | sq)

  k_prep<<<576, 256, 0, stream>>>(w10, w01, w02, w12, wT10, wT01, wT02, wT12, stats);
  k_gemm10p<<<2048, 256, 0, stream>>>(data1, wT10, y10, p1);
  k_stats10<<<128, 192, 0, stream>>>(y10, stats);
  k_out0<<<8192, 256, 0, stream>>>(data0, y10, stats, g10, b10, out0, p0, p00);
  k_statsAll<<<1280, 256, 0, stream>>>(p0, p00, p1, wT01, wT02, wT12, stats);
  k_out1<<<2048, 256, 0, stream>>>(p0, wT01, data1, stats, g01, b01, out1);
  k_out2<<<256, 256, 0, stream>>>(p00, p1, wT02, wT12, stats, g02, b02, g12, b12, out2);
}